// Round 1
// baseline (1333.981 us; speedup 1.0000x reference)
//
#include <hip/hip_runtime.h>

#define NPFAS 50000
#define NGW   200000
#define NSW   20000
#define D     32
#define EPG   2000000
#define EGP   2000000
#define EPS   1000000
#define ESP   1000000

// ---------------- edge aggregation: 32 lanes per edge ----------------
// s[dst][lane] += x_src[src][lane]; cnt[dst] += 1; maxe[dst] = max(edge id)
__global__ __launch_bounds__(256) void edge_agg(
    const float* __restrict__ x_src,
    const int* __restrict__ src,
    const int* __restrict__ dst,
    float* __restrict__ s,
    float* __restrict__ cnt,
    int* __restrict__ maxe,
    int E)
{
    int t = blockIdx.x * blockDim.x + threadIdx.x;
    int e = t >> 5;
    int lane = t & 31;
    if (e >= E) return;
    int sn = src[e];
    int dn = dst[e];
    float v = x_src[(size_t)sn * D + lane];
    atomicAdd(&s[(size_t)dn * D + lane], v);
    if (lane == 0) {
        atomicAdd(&cnt[dn], 1.0f);
        if (maxe) atomicMax(&maxe[dn], e);
    }
}

// ---------------- finalize gw: sage(pg) + edge set + relu + head ----------------
__global__ __launch_bounds__(256) void finalize_gw(
    const float* __restrict__ s, const float* __restrict__ cnt,
    const int* __restrict__ maxe,
    const float* __restrict__ x_gw,
    const float* __restrict__ ea,
    const float* __restrict__ Wl, const float* __restrict__ bl,
    const float* __restrict__ Wr, const float* __restrict__ We,
    const float* __restrict__ be,
    const float* __restrict__ W_out, const float* __restrict__ b_out,
    const float* __restrict__ a_prelu,
    float* __restrict__ y_out)
{
    __shared__ __align__(16) float WlT[D * D];   // WlT[j*D+k] = Wl[k*D+j]
    __shared__ __align__(16) float WrT[D * D];
    __shared__ float WeT[3 * D];                 // WeT[j*3+k] = We[k*D+j]
    __shared__ float blS[D], beS[D], WoS[D];
    for (int i = threadIdx.x; i < D * D; i += blockDim.x) {
        int k = i / D, j = i % D;
        WlT[j * D + k] = Wl[i];
        WrT[j * D + k] = Wr[i];
    }
    for (int i = threadIdx.x; i < 3 * D; i += blockDim.x) {
        int k = i / D, j = i % D;
        WeT[j * 3 + k] = We[i];
    }
    if (threadIdx.x < D) {
        blS[threadIdx.x] = bl[threadIdx.x];
        beS[threadIdx.x] = be[threadIdx.x];
        WoS[threadIdx.x] = W_out[threadIdx.x];
    }
    __syncthreads();

    int n = blockIdx.x * blockDim.x + threadIdx.x;
    if (n >= NGW) return;

    float mean[D], xd[D];
    float inv = 1.0f / fmaxf(cnt[n], 1.0f);
    const float4* sp = (const float4*)(s + (size_t)n * D);
    const float4* xp = (const float4*)(x_gw + (size_t)n * D);
#pragma unroll
    for (int q = 0; q < D / 4; q++) {
        float4 sv = sp[q];
        mean[4*q+0] = sv.x * inv; mean[4*q+1] = sv.y * inv;
        mean[4*q+2] = sv.z * inv; mean[4*q+3] = sv.w * inv;
        float4 xv = xp[q];
        xd[4*q+0] = xv.x; xd[4*q+1] = xv.y; xd[4*q+2] = xv.z; xd[4*q+3] = xv.w;
    }
    int me = maxe[n];
    bool he = (me >= 0);
    float e0 = 0.f, e1 = 0.f, e2 = 0.f;
    if (he) {
        e0 = ea[(size_t)me * 3 + 0];
        e1 = ea[(size_t)me * 3 + 1];
        e2 = ea[(size_t)me * 3 + 2];
    }
    float yacc = 0.f;
    for (int j = 0; j < D; j++) {
        float o = blS[j] + (he ? beS[j] : 0.0f);
        const float4* wl4 = (const float4*)(WlT + j * D);
        const float4* wr4 = (const float4*)(WrT + j * D);
#pragma unroll
        for (int q = 0; q < D / 4; q++) {
            float4 wl = wl4[q], wr = wr4[q];
            o += mean[4*q+0]*wl.x + mean[4*q+1]*wl.y + mean[4*q+2]*wl.z + mean[4*q+3]*wl.w;
            o += xd[4*q+0]*wr.x + xd[4*q+1]*wr.y + xd[4*q+2]*wr.z + xd[4*q+3]*wr.w;
        }
        if (he) o += e0*WeT[j*3+0] + e1*WeT[j*3+1] + e2*WeT[j*3+2];
        float h = fmaxf(o, 0.0f);
        yacc += h * WoS[j];
    }
    float y = yacc + b_out[0];
    float ap = a_prelu[0];
    y_out[n] = (y >= 0.f) ? y : ap * y;
}

// ---------------- finalize pfas: sage(gp)+edge set + sage(sp), relu ----------------
__global__ __launch_bounds__(256) void finalize_pfas(
    const float* __restrict__ s_gp, const float* __restrict__ cnt_gp,
    const int* __restrict__ maxe_gp,
    const float* __restrict__ s_sp, const float* __restrict__ cnt_sp,
    const float* __restrict__ x_pfas,
    const float* __restrict__ ea,
    const float* __restrict__ Wl_gp, const float* __restrict__ bl_gp,
    const float* __restrict__ Wr_gp, const float* __restrict__ We_gp,
    const float* __restrict__ be_gp,
    const float* __restrict__ Wl_sp, const float* __restrict__ bl_sp,
    const float* __restrict__ Wr_sp,
    float* __restrict__ h_out)
{
    __shared__ __align__(16) float WlgT[D * D];
    __shared__ __align__(16) float WlsT[D * D];
    __shared__ __align__(16) float WrcT[D * D];   // (Wr_gp + Wr_sp)^T
    __shared__ float WeT[3 * D];
    __shared__ float blc[D], beS[D];
    for (int i = threadIdx.x; i < D * D; i += blockDim.x) {
        int k = i / D, j = i % D;
        WlgT[j * D + k] = Wl_gp[i];
        WlsT[j * D + k] = Wl_sp[i];
        WrcT[j * D + k] = Wr_gp[i] + Wr_sp[i];
    }
    for (int i = threadIdx.x; i < 3 * D; i += blockDim.x) {
        int k = i / D, j = i % D;
        WeT[j * 3 + k] = We_gp[i];
    }
    if (threadIdx.x < D) {
        blc[threadIdx.x] = bl_gp[threadIdx.x] + bl_sp[threadIdx.x];
        beS[threadIdx.x] = be_gp[threadIdx.x];
    }
    __syncthreads();

    int n = blockIdx.x * blockDim.x + threadIdx.x;
    if (n >= NPFAS) return;

    float mg[D], ms[D], xd[D];
    float invg = 1.0f / fmaxf(cnt_gp[n], 1.0f);
    float invs = 1.0f / fmaxf(cnt_sp[n], 1.0f);
    const float4* gp4 = (const float4*)(s_gp + (size_t)n * D);
    const float4* sp4 = (const float4*)(s_sp + (size_t)n * D);
    const float4* xp4 = (const float4*)(x_pfas + (size_t)n * D);
#pragma unroll
    for (int q = 0; q < D / 4; q++) {
        float4 a = gp4[q];
        mg[4*q+0] = a.x * invg; mg[4*q+1] = a.y * invg; mg[4*q+2] = a.z * invg; mg[4*q+3] = a.w * invg;
        float4 b = sp4[q];
        ms[4*q+0] = b.x * invs; ms[4*q+1] = b.y * invs; ms[4*q+2] = b.z * invs; ms[4*q+3] = b.w * invs;
        float4 c = xp4[q];
        xd[4*q+0] = c.x; xd[4*q+1] = c.y; xd[4*q+2] = c.z; xd[4*q+3] = c.w;
    }
    int me = maxe_gp[n];
    bool he = (me >= 0);
    float e0 = 0.f, e1 = 0.f, e2 = 0.f;
    if (he) {
        e0 = ea[(size_t)me * 3 + 0];
        e1 = ea[(size_t)me * 3 + 1];
        e2 = ea[(size_t)me * 3 + 2];
    }
    float* out = h_out + (size_t)n * D;
    for (int j = 0; j < D; j++) {
        float o = blc[j] + (he ? beS[j] : 0.0f);
        const float4* wg4 = (const float4*)(WlgT + j * D);
        const float4* ws4 = (const float4*)(WlsT + j * D);
        const float4* wc4 = (const float4*)(WrcT + j * D);
#pragma unroll
        for (int q = 0; q < D / 4; q++) {
            float4 wg = wg4[q], wsv = ws4[q], wc = wc4[q];
            o += mg[4*q+0]*wg.x + mg[4*q+1]*wg.y + mg[4*q+2]*wg.z + mg[4*q+3]*wg.w;
            o += ms[4*q+0]*wsv.x + ms[4*q+1]*wsv.y + ms[4*q+2]*wsv.z + ms[4*q+3]*wsv.w;
            o += xd[4*q+0]*wc.x + xd[4*q+1]*wc.y + xd[4*q+2]*wc.z + xd[4*q+3]*wc.w;
        }
        if (he) o += e0*WeT[j*3+0] + e1*WeT[j*3+1] + e2*WeT[j*3+2];
        out[j] = fmaxf(o, 0.0f);
    }
}

// ---------------- finalize sw: plain sage(ps), relu ----------------
__global__ __launch_bounds__(256) void finalize_sw(
    const float* __restrict__ s, const float* __restrict__ cnt,
    const float* __restrict__ x_sw,
    const float* __restrict__ Wl, const float* __restrict__ bl,
    const float* __restrict__ Wr,
    float* __restrict__ h_out)
{
    __shared__ __align__(16) float WlT[D * D];
    __shared__ __align__(16) float WrT[D * D];
    __shared__ float blS[D];
    for (int i = threadIdx.x; i < D * D; i += blockDim.x) {
        int k = i / D, j = i % D;
        WlT[j * D + k] = Wl[i];
        WrT[j * D + k] = Wr[i];
    }
    if (threadIdx.x < D) blS[threadIdx.x] = bl[threadIdx.x];
    __syncthreads();

    int n = blockIdx.x * blockDim.x + threadIdx.x;
    if (n >= NSW) return;

    float mean[D], xd[D];
    float inv = 1.0f / fmaxf(cnt[n], 1.0f);
    const float4* sp = (const float4*)(s + (size_t)n * D);
    const float4* xp = (const float4*)(x_sw + (size_t)n * D);
#pragma unroll
    for (int q = 0; q < D / 4; q++) {
        float4 sv = sp[q];
        mean[4*q+0] = sv.x * inv; mean[4*q+1] = sv.y * inv;
        mean[4*q+2] = sv.z * inv; mean[4*q+3] = sv.w * inv;
        float4 xv = xp[q];
        xd[4*q+0] = xv.x; xd[4*q+1] = xv.y; xd[4*q+2] = xv.z; xd[4*q+3] = xv.w;
    }
    float* out = h_out + (size_t)n * D;
    for (int j = 0; j < D; j++) {
        float o = blS[j];
        const float4* wl4 = (const float4*)(WlT + j * D);
        const float4* wr4 = (const float4*)(WrT + j * D);
#pragma unroll
        for (int q = 0; q < D / 4; q++) {
            float4 wl = wl4[q], wr = wr4[q];
            o += mean[4*q+0]*wl.x + mean[4*q+1]*wl.y + mean[4*q+2]*wl.z + mean[4*q+3]*wl.w;
            o += xd[4*q+0]*wr.x + xd[4*q+1]*wr.y + xd[4*q+2]*wr.z + xd[4*q+3]*wr.w;
        }
        out[j] = fmaxf(o, 0.0f);
    }
}

extern "C" void kernel_launch(void* const* d_in, const int* in_sizes, int n_in,
                              void* d_out, int out_size, void* d_ws, size_t ws_size,
                              hipStream_t stream) {
    (void)in_sizes; (void)n_in; (void)out_size; (void)ws_size;
    const float* x_pfas = (const float*)d_in[0];
    const float* x_gw   = (const float*)d_in[1];
    const float* x_sw   = (const float*)d_in[2];
    const int*   src_pg = (const int*)d_in[3];
    const int*   dst_pg = (const int*)d_in[4];
    const float* ea_pg  = (const float*)d_in[5];
    const int*   src_gp = (const int*)d_in[6];
    const int*   dst_gp = (const int*)d_in[7];
    const float* ea_gp  = (const float*)d_in[8];
    const int*   src_ps = (const int*)d_in[9];
    const int*   dst_ps = (const int*)d_in[10];
    const int*   src_sp = (const int*)d_in[11];
    const int*   dst_sp = (const int*)d_in[12];
    const float* Wl_pg = (const float*)d_in[13];
    const float* bl_pg = (const float*)d_in[14];
    const float* Wr_pg = (const float*)d_in[15];
    const float* We_pg = (const float*)d_in[16];
    const float* be_pg = (const float*)d_in[17];
    const float* Wl_gp = (const float*)d_in[18];
    const float* bl_gp = (const float*)d_in[19];
    const float* Wr_gp = (const float*)d_in[20];
    const float* We_gp = (const float*)d_in[21];
    const float* be_gp = (const float*)d_in[22];
    const float* Wl_ps = (const float*)d_in[23];
    const float* bl_ps = (const float*)d_in[24];
    const float* Wr_ps = (const float*)d_in[25];
    const float* Wl_sp = (const float*)d_in[26];
    const float* bl_sp = (const float*)d_in[27];
    const float* Wr_sp = (const float*)d_in[28];
    const float* W_out = (const float*)d_in[29];
    const float* b_out = (const float*)d_in[30];
    const float* a_pre = (const float*)d_in[31];

    // workspace layout (floats)
    float* ws = (float*)d_ws;
    float* s_pg   = ws;                  // 6,400,000
    float* s_gp   = ws + 6400000;        // 1,600,000
    float* s_sp   = ws + 8000000;        // 1,600,000
    float* s_ps   = ws + 9600000;        //   640,000
    float* cnt_pg = ws + 10240000;       //   200,000
    float* cnt_gp = ws + 10440000;       //    50,000
    float* cnt_sp = ws + 10490000;       //    50,000
    float* cnt_ps = ws + 10540000;       //    20,000
    int*   maxe_pg = (int*)(ws + 10560000); // 200,000
    int*   maxe_gp = (int*)(ws + 10760000); //  50,000

    hipMemsetAsync(ws, 0, (size_t)10560000 * sizeof(float), stream);
    hipMemsetAsync(maxe_pg, 0xFF, (size_t)250000 * sizeof(int), stream);

    // edge aggregation (32 lanes per edge)
    {
        int blocks = (EPG * 32 + 255) / 256;
        edge_agg<<<blocks, 256, 0, stream>>>(x_pfas, src_pg, dst_pg, s_pg, cnt_pg, maxe_pg, EPG);
    }
    {
        int blocks = (EGP * 32 + 255) / 256;
        edge_agg<<<blocks, 256, 0, stream>>>(x_gw, src_gp, dst_gp, s_gp, cnt_gp, maxe_gp, EGP);
    }
    {
        int blocks = (ESP * 32 + 255) / 256;
        edge_agg<<<blocks, 256, 0, stream>>>(x_sw, src_sp, dst_sp, s_sp, cnt_sp, (int*)nullptr, ESP);
    }
    {
        int blocks = (EPS * 32 + 255) / 256;
        edge_agg<<<blocks, 256, 0, stream>>>(x_pfas, src_ps, dst_ps, s_ps, cnt_ps, (int*)nullptr, EPS);
    }

    // output layout: h_pfas [50000*32] | y [200000] | h_sw [20000*32]
    float* out    = (float*)d_out;
    float* h_pfas = out;
    float* y_out  = out + 1600000;
    float* h_sw   = out + 1800000;

    finalize_pfas<<<(NPFAS + 255) / 256, 256, 0, stream>>>(
        s_gp, cnt_gp, maxe_gp, s_sp, cnt_sp, x_pfas, ea_gp,
        Wl_gp, bl_gp, Wr_gp, We_gp, be_gp,
        Wl_sp, bl_sp, Wr_sp, h_pfas);

    finalize_gw<<<(NGW + 255) / 256, 256, 0, stream>>>(
        s_pg, cnt_pg, maxe_pg, x_gw, ea_pg,
        Wl_pg, bl_pg, Wr_pg, We_pg, be_pg,
        W_out, b_out, a_pre, y_out);

    finalize_sw<<<(NSW + 255) / 256, 256, 0, stream>>>(
        s_ps, cnt_ps, x_sw, Wl_ps, bl_ps, Wr_ps, h_sw);
}

// Round 2
// 1274.029 us; speedup vs baseline: 1.0471x; 1.0471x over previous
//
#include <hip/hip_runtime.h>

#define NPFAS 50000
#define NGW   200000
#define NSW   20000
#define D     32
#define EPG   2000000
#define EGP   2000000
#define EPS   1000000
#define ESP   1000000
#define ETOT  (EPG + EGP + ESP + EPS)

// ---- workspace layout (element offsets, 4B units) ----
#define S_PG    0           // 6,400,000 f
#define S_GP    6400000     // 1,600,000 f
#define S_SP    8000000     // 1,600,000 f
#define S_PS    9600000     //   640,000 f
#define CSR_PG  10240000    // 2,000,000 i
#define CSR_GP  12240000    // 2,000,000 i
#define CSR_SP  14240000    // 1,000,000 i
#define CSR_PS  15240000    // 1,000,000 i
#define PTR_PG  16240000    // 200,001 i
#define PTR_GP  16440001    //  50,001 i
#define PTR_SP  16490002    //  50,001 i
#define PTR_PS  16540003    //  20,001 i
#define CUR_PG  16560004    // 200,000 i   (counts, then offsets-cursor)
#define CUR_GP  16760004    //  50,000 i
#define CUR_SP  16810004    //  50,000 i
#define CUR_PS  16860004    //  20,000 i
#define MAXE_PG 16880004    // 200,000 i
#define MAXE_GP 17080004    //  50,000 i
#define BSUM    17130004    // 4 * 128 i
// total ~17,130,520 elems = ~65.3 MiB

#define SCAN_CHUNK 2048
#define NB_PG 98   // ceil(200000/2048)
#define NB_GP 25
#define NB_SP 25
#define NB_PS 10

// ---------------- histogram + last-edge (max id) ----------------
__global__ __launch_bounds__(256) void hist_all(
    const int* __restrict__ dst_pg, const int* __restrict__ dst_gp,
    const int* __restrict__ dst_sp, const int* __restrict__ dst_ps,
    int* __restrict__ wsi)
{
    int e = blockIdx.x * 256 + threadIdx.x;
    if (e >= ETOT) return;
    if (e < EPG) {
        int d = dst_pg[e];
        atomicAdd(&wsi[CUR_PG + d], 1);
        atomicMax(&wsi[MAXE_PG + d], e);
        return;
    }
    e -= EPG;
    if (e < EGP) {
        int d = dst_gp[e];
        atomicAdd(&wsi[CUR_GP + d], 1);
        atomicMax(&wsi[MAXE_GP + d], e);
        return;
    }
    e -= EGP;
    if (e < ESP) {
        int d = dst_sp[e];
        atomicAdd(&wsi[CUR_SP + d], 1);
        return;
    }
    e -= ESP;
    int d = dst_ps[e];
    atomicAdd(&wsi[CUR_PS + d], 1);
}

// ---------------- scan phase 1: per-chunk local exclusive scan ----------------
__device__ __forceinline__ void scan1_one(const int* __restrict__ cnt,
                                          int* __restrict__ ptr,
                                          int* __restrict__ bsum,
                                          int chunk, int n)
{
    __shared__ int sh[256];
    int t = threadIdx.x;
    int base = chunk * SCAN_CHUNK;
    int vals[8];
    int tsum = 0;
#pragma unroll
    for (int i = 0; i < 8; i++) {
        int idx = base + t * 8 + i;
        int v = (idx < n) ? cnt[idx] : 0;
        vals[i] = tsum;
        tsum += v;
    }
    sh[t] = tsum;
    __syncthreads();
    for (int off = 1; off < 256; off <<= 1) {
        int v = (t >= off) ? sh[t - off] : 0;
        __syncthreads();
        sh[t] += v;
        __syncthreads();
    }
    int texcl = sh[t] - tsum;   // exclusive prefix of this thread
#pragma unroll
    for (int i = 0; i < 8; i++) {
        int idx = base + t * 8 + i;
        if (idx < n) ptr[idx] = texcl + vals[i];
    }
    if (t == 255) bsum[chunk] = sh[255];
}

__global__ __launch_bounds__(256) void scan1_all(int* __restrict__ wsi)
{
    int b = blockIdx.x;
    if (b < NB_PG) { scan1_one(wsi + CUR_PG, wsi + PTR_PG, wsi + BSUM + 0,   b, NGW);   return; }
    b -= NB_PG;
    if (b < NB_GP) { scan1_one(wsi + CUR_GP, wsi + PTR_GP, wsi + BSUM + 128, b, NPFAS); return; }
    b -= NB_GP;
    if (b < NB_SP) { scan1_one(wsi + CUR_SP, wsi + PTR_SP, wsi + BSUM + 256, b, NPFAS); return; }
    b -= NB_SP;
    scan1_one(wsi + CUR_PS, wsi + PTR_PS, wsi + BSUM + 384, b, NSW);
}

// ---------------- scan phase 2: scan the block sums (tiny, serial) ----------------
__global__ void scan2_all(int* __restrict__ wsi)
{
    if (threadIdx.x != 0) return;
    int r = blockIdx.x;
    int nb = (r == 0) ? NB_PG : (r == 1) ? NB_GP : (r == 2) ? NB_SP : NB_PS;
    int* b = wsi + BSUM + r * 128;
    int acc = 0;
    for (int i = 0; i < nb; i++) { int v = b[i]; b[i] = acc; acc += v; }
}

// ---------------- scan phase 3: add chunk offsets, write cursor copy ----------------
__device__ __forceinline__ void scan3_one(int* __restrict__ ptr,
                                          int* __restrict__ cur,
                                          const int* __restrict__ bsum,
                                          int i, int n, int E)
{
    if (i < n) {
        int v = ptr[i] + bsum[i >> 11];
        ptr[i] = v;
        cur[i] = v;
    } else {
        ptr[n] = E;
    }
}

__global__ __launch_bounds__(256) void scan3_all(int* __restrict__ wsi)
{
    int i = blockIdx.x * 256 + threadIdx.x;
    if (i < NGW + 1) { scan3_one(wsi + PTR_PG, wsi + CUR_PG, wsi + BSUM + 0,   i, NGW,   EPG); return; }
    i -= NGW + 1;
    if (i < NPFAS + 1) { scan3_one(wsi + PTR_GP, wsi + CUR_GP, wsi + BSUM + 128, i, NPFAS, EGP); return; }
    i -= NPFAS + 1;
    if (i < NPFAS + 1) { scan3_one(wsi + PTR_SP, wsi + CUR_SP, wsi + BSUM + 256, i, NPFAS, ESP); return; }
    i -= NPFAS + 1;
    if (i < NSW + 1) { scan3_one(wsi + PTR_PS, wsi + CUR_PS, wsi + BSUM + 384, i, NSW, EPS); }
}

// ---------------- scatter src ids into CSR order ----------------
__global__ __launch_bounds__(256) void scatter_all(
    const int* __restrict__ src_pg, const int* __restrict__ dst_pg,
    const int* __restrict__ src_gp, const int* __restrict__ dst_gp,
    const int* __restrict__ src_sp, const int* __restrict__ dst_sp,
    const int* __restrict__ src_ps, const int* __restrict__ dst_ps,
    int* __restrict__ wsi)
{
    int e = blockIdx.x * 256 + threadIdx.x;
    if (e >= ETOT) return;
    if (e < EPG) {
        int pos = atomicAdd(&wsi[CUR_PG + dst_pg[e]], 1);
        wsi[CSR_PG + pos] = src_pg[e];
        return;
    }
    e -= EPG;
    if (e < EGP) {
        int pos = atomicAdd(&wsi[CUR_GP + dst_gp[e]], 1);
        wsi[CSR_GP + pos] = src_gp[e];
        return;
    }
    e -= EGP;
    if (e < ESP) {
        int pos = atomicAdd(&wsi[CUR_SP + dst_sp[e]], 1);
        wsi[CSR_SP + pos] = src_sp[e];
        return;
    }
    e -= ESP;
    int pos = atomicAdd(&wsi[CUR_PS + dst_ps[e]], 1);
    wsi[CSR_PS + pos] = src_ps[e];
}

// ---------------- dst-centric gather: 32 lanes per node ----------------
__device__ __forceinline__ void gather_one(
    const float* __restrict__ x, const int* __restrict__ ptr,
    const int* __restrict__ csr, float* __restrict__ s,
    int g, int lane)
{
    int p0 = ptr[g], p1 = ptr[g + 1];
    float acc = 0.f;
    for (int base = p0; base < p1; base += 32) {
        int m = p1 - base; if (m > 32) m = 32;
        int sid = (lane < m) ? csr[base + lane] : 0;
        int i = 0;
        for (; i + 4 <= m; i += 4) {
            int a = __shfl(sid, i, 32);
            int b = __shfl(sid, i + 1, 32);
            int c = __shfl(sid, i + 2, 32);
            int d = __shfl(sid, i + 3, 32);
            float v0 = x[(size_t)a * D + lane];
            float v1 = x[(size_t)b * D + lane];
            float v2 = x[(size_t)c * D + lane];
            float v3 = x[(size_t)d * D + lane];
            acc += v0 + v1 + v2 + v3;
        }
        for (; i < m; i++) {
            acc += x[(size_t)__shfl(sid, i, 32) * D + lane];
        }
    }
    s[(size_t)g * D + lane] = acc;
}

__global__ __launch_bounds__(256) void gather_all(
    const float* __restrict__ x_pfas, const float* __restrict__ x_gw,
    const float* __restrict__ x_sw, int* __restrict__ wsi)
{
    float* wsf = (float*)wsi;
    int g = (blockIdx.x * 256 + threadIdx.x) >> 5;
    int lane = threadIdx.x & 31;
    if (g < NGW) { gather_one(x_pfas, wsi + PTR_PG, wsi + CSR_PG, wsf + S_PG, g, lane); return; }
    g -= NGW;
    if (g < NPFAS) { gather_one(x_gw, wsi + PTR_GP, wsi + CSR_GP, wsf + S_GP, g, lane); return; }
    g -= NPFAS;
    if (g < NPFAS) { gather_one(x_sw, wsi + PTR_SP, wsi + CSR_SP, wsf + S_SP, g, lane); return; }
    g -= NPFAS;
    if (g < NSW) { gather_one(x_pfas, wsi + PTR_PS, wsi + CSR_PS, wsf + S_PS, g, lane); }
}

// ---------------- finalize gw: sage(pg) + edge set + relu + head ----------------
__global__ __launch_bounds__(256) void finalize_gw(
    const float* __restrict__ s, const int* __restrict__ ptr,
    const int* __restrict__ maxe,
    const float* __restrict__ x_gw,
    const float* __restrict__ ea,
    const float* __restrict__ Wl, const float* __restrict__ bl,
    const float* __restrict__ Wr, const float* __restrict__ We,
    const float* __restrict__ be,
    const float* __restrict__ W_out, const float* __restrict__ b_out,
    const float* __restrict__ a_prelu,
    float* __restrict__ y_out)
{
    __shared__ __align__(16) float WlT[D * D];   // WlT[j*D+k] = Wl[k*D+j]
    __shared__ __align__(16) float WrT[D * D];
    __shared__ float WeT[3 * D];
    __shared__ float blS[D], beS[D], WoS[D];
    for (int i = threadIdx.x; i < D * D; i += blockDim.x) {
        int k = i / D, j = i % D;
        WlT[j * D + k] = Wl[i];
        WrT[j * D + k] = Wr[i];
    }
    for (int i = threadIdx.x; i < 3 * D; i += blockDim.x) {
        int k = i / D, j = i % D;
        WeT[j * 3 + k] = We[i];
    }
    if (threadIdx.x < D) {
        blS[threadIdx.x] = bl[threadIdx.x];
        beS[threadIdx.x] = be[threadIdx.x];
        WoS[threadIdx.x] = W_out[threadIdx.x];
    }
    __syncthreads();

    int n = blockIdx.x * blockDim.x + threadIdx.x;
    if (n >= NGW) return;

    float mean[D], xd[D];
    float inv = 1.0f / fmaxf((float)(ptr[n + 1] - ptr[n]), 1.0f);
    const float4* sp = (const float4*)(s + (size_t)n * D);
    const float4* xp = (const float4*)(x_gw + (size_t)n * D);
#pragma unroll
    for (int q = 0; q < D / 4; q++) {
        float4 sv = sp[q];
        mean[4*q+0] = sv.x * inv; mean[4*q+1] = sv.y * inv;
        mean[4*q+2] = sv.z * inv; mean[4*q+3] = sv.w * inv;
        float4 xv = xp[q];
        xd[4*q+0] = xv.x; xd[4*q+1] = xv.y; xd[4*q+2] = xv.z; xd[4*q+3] = xv.w;
    }
    int me = maxe[n];
    bool he = (me >= 0);
    float e0 = 0.f, e1 = 0.f, e2 = 0.f;
    if (he) {
        e0 = ea[(size_t)me * 3 + 0];
        e1 = ea[(size_t)me * 3 + 1];
        e2 = ea[(size_t)me * 3 + 2];
    }
    float yacc = 0.f;
    for (int j = 0; j < D; j++) {
        float o = blS[j] + (he ? beS[j] : 0.0f);
        const float4* wl4 = (const float4*)(WlT + j * D);
        const float4* wr4 = (const float4*)(WrT + j * D);
#pragma unroll
        for (int q = 0; q < D / 4; q++) {
            float4 wl = wl4[q], wr = wr4[q];
            o += mean[4*q+0]*wl.x + mean[4*q+1]*wl.y + mean[4*q+2]*wl.z + mean[4*q+3]*wl.w;
            o += xd[4*q+0]*wr.x + xd[4*q+1]*wr.y + xd[4*q+2]*wr.z + xd[4*q+3]*wr.w;
        }
        if (he) o += e0*WeT[j*3+0] + e1*WeT[j*3+1] + e2*WeT[j*3+2];
        float h = fmaxf(o, 0.0f);
        yacc += h * WoS[j];
    }
    float y = yacc + b_out[0];
    float ap = a_prelu[0];
    y_out[n] = (y >= 0.f) ? y : ap * y;
}

// ---------------- finalize pfas: sage(gp)+edge set + sage(sp), relu ----------------
__global__ __launch_bounds__(256) void finalize_pfas(
    const float* __restrict__ s_gp, const int* __restrict__ ptr_gp,
    const int* __restrict__ maxe_gp,
    const float* __restrict__ s_sp, const int* __restrict__ ptr_sp,
    const float* __restrict__ x_pfas,
    const float* __restrict__ ea,
    const float* __restrict__ Wl_gp, const float* __restrict__ bl_gp,
    const float* __restrict__ Wr_gp, const float* __restrict__ We_gp,
    const float* __restrict__ be_gp,
    const float* __restrict__ Wl_sp, const float* __restrict__ bl_sp,
    const float* __restrict__ Wr_sp,
    float* __restrict__ h_out)
{
    __shared__ __align__(16) float WlgT[D * D];
    __shared__ __align__(16) float WlsT[D * D];
    __shared__ __align__(16) float WrcT[D * D];   // (Wr_gp + Wr_sp)^T
    __shared__ float WeT[3 * D];
    __shared__ float blc[D], beS[D];
    for (int i = threadIdx.x; i < D * D; i += blockDim.x) {
        int k = i / D, j = i % D;
        WlgT[j * D + k] = Wl_gp[i];
        WlsT[j * D + k] = Wl_sp[i];
        WrcT[j * D + k] = Wr_gp[i] + Wr_sp[i];
    }
    for (int i = threadIdx.x; i < 3 * D; i += blockDim.x) {
        int k = i / D, j = i % D;
        WeT[j * 3 + k] = We_gp[i];
    }
    if (threadIdx.x < D) {
        blc[threadIdx.x] = bl_gp[threadIdx.x] + bl_sp[threadIdx.x];
        beS[threadIdx.x] = be_gp[threadIdx.x];
    }
    __syncthreads();

    int n = blockIdx.x * blockDim.x + threadIdx.x;
    if (n >= NPFAS) return;

    float mg[D], ms[D], xd[D];
    float invg = 1.0f / fmaxf((float)(ptr_gp[n + 1] - ptr_gp[n]), 1.0f);
    float invs = 1.0f / fmaxf((float)(ptr_sp[n + 1] - ptr_sp[n]), 1.0f);
    const float4* gp4 = (const float4*)(s_gp + (size_t)n * D);
    const float4* sp4 = (const float4*)(s_sp + (size_t)n * D);
    const float4* xp4 = (const float4*)(x_pfas + (size_t)n * D);
#pragma unroll
    for (int q = 0; q < D / 4; q++) {
        float4 a = gp4[q];
        mg[4*q+0] = a.x * invg; mg[4*q+1] = a.y * invg; mg[4*q+2] = a.z * invg; mg[4*q+3] = a.w * invg;
        float4 b = sp4[q];
        ms[4*q+0] = b.x * invs; ms[4*q+1] = b.y * invs; ms[4*q+2] = b.z * invs; ms[4*q+3] = b.w * invs;
        float4 c = xp4[q];
        xd[4*q+0] = c.x; xd[4*q+1] = c.y; xd[4*q+2] = c.z; xd[4*q+3] = c.w;
    }
    int me = maxe_gp[n];
    bool he = (me >= 0);
    float e0 = 0.f, e1 = 0.f, e2 = 0.f;
    if (he) {
        e0 = ea[(size_t)me * 3 + 0];
        e1 = ea[(size_t)me * 3 + 1];
        e2 = ea[(size_t)me * 3 + 2];
    }
    float* out = h_out + (size_t)n * D;
    for (int j = 0; j < D; j++) {
        float o = blc[j] + (he ? beS[j] : 0.0f);
        const float4* wg4 = (const float4*)(WlgT + j * D);
        const float4* ws4 = (const float4*)(WlsT + j * D);
        const float4* wc4 = (const float4*)(WrcT + j * D);
#pragma unroll
        for (int q = 0; q < D / 4; q++) {
            float4 wg = wg4[q], wsv = ws4[q], wc = wc4[q];
            o += mg[4*q+0]*wg.x + mg[4*q+1]*wg.y + mg[4*q+2]*wg.z + mg[4*q+3]*wg.w;
            o += ms[4*q+0]*wsv.x + ms[4*q+1]*wsv.y + ms[4*q+2]*wsv.z + ms[4*q+3]*wsv.w;
            o += xd[4*q+0]*wc.x + xd[4*q+1]*wc.y + xd[4*q+2]*wc.z + xd[4*q+3]*wc.w;
        }
        if (he) o += e0*WeT[j*3+0] + e1*WeT[j*3+1] + e2*WeT[j*3+2];
        out[j] = fmaxf(o, 0.0f);
    }
}

// ---------------- finalize sw: plain sage(ps), relu ----------------
__global__ __launch_bounds__(256) void finalize_sw(
    const float* __restrict__ s, const int* __restrict__ ptr,
    const float* __restrict__ x_sw,
    const float* __restrict__ Wl, const float* __restrict__ bl,
    const float* __restrict__ Wr,
    float* __restrict__ h_out)
{
    __shared__ __align__(16) float WlT[D * D];
    __shared__ __align__(16) float WrT[D * D];
    __shared__ float blS[D];
    for (int i = threadIdx.x; i < D * D; i += blockDim.x) {
        int k = i / D, j = i % D;
        WlT[j * D + k] = Wl[i];
        WrT[j * D + k] = Wr[i];
    }
    if (threadIdx.x < D) blS[threadIdx.x] = bl[threadIdx.x];
    __syncthreads();

    int n = blockIdx.x * blockDim.x + threadIdx.x;
    if (n >= NSW) return;

    float mean[D], xd[D];
    float inv = 1.0f / fmaxf((float)(ptr[n + 1] - ptr[n]), 1.0f);
    const float4* sp = (const float4*)(s + (size_t)n * D);
    const float4* xp = (const float4*)(x_sw + (size_t)n * D);
#pragma unroll
    for (int q = 0; q < D / 4; q++) {
        float4 sv = sp[q];
        mean[4*q+0] = sv.x * inv; mean[4*q+1] = sv.y * inv;
        mean[4*q+2] = sv.z * inv; mean[4*q+3] = sv.w * inv;
        float4 xv = xp[q];
        xd[4*q+0] = xv.x; xd[4*q+1] = xv.y; xd[4*q+2] = xv.z; xd[4*q+3] = xv.w;
    }
    float* out = h_out + (size_t)n * D;
    for (int j = 0; j < D; j++) {
        float o = blS[j];
        const float4* wl4 = (const float4*)(WlT + j * D);
        const float4* wr4 = (const float4*)(WrT + j * D);
#pragma unroll
        for (int q = 0; q < D / 4; q++) {
            float4 wl = wl4[q], wr = wr4[q];
            o += mean[4*q+0]*wl.x + mean[4*q+1]*wl.y + mean[4*q+2]*wl.z + mean[4*q+3]*wl.w;
            o += xd[4*q+0]*wr.x + xd[4*q+1]*wr.y + xd[4*q+2]*wr.z + xd[4*q+3]*wr.w;
        }
        out[j] = fmaxf(o, 0.0f);
    }
}

extern "C" void kernel_launch(void* const* d_in, const int* in_sizes, int n_in,
                              void* d_out, int out_size, void* d_ws, size_t ws_size,
                              hipStream_t stream) {
    (void)in_sizes; (void)n_in; (void)out_size; (void)ws_size;
    const float* x_pfas = (const float*)d_in[0];
    const float* x_gw   = (const float*)d_in[1];
    const float* x_sw   = (const float*)d_in[2];
    const int*   src_pg = (const int*)d_in[3];
    const int*   dst_pg = (const int*)d_in[4];
    const float* ea_pg  = (const float*)d_in[5];
    const int*   src_gp = (const int*)d_in[6];
    const int*   dst_gp = (const int*)d_in[7];
    const float* ea_gp  = (const float*)d_in[8];
    const int*   src_ps = (const int*)d_in[9];
    const int*   dst_ps = (const int*)d_in[10];
    const int*   src_sp = (const int*)d_in[11];
    const int*   dst_sp = (const int*)d_in[12];
    const float* Wl_pg = (const float*)d_in[13];
    const float* bl_pg = (const float*)d_in[14];
    const float* Wr_pg = (const float*)d_in[15];
    const float* We_pg = (const float*)d_in[16];
    const float* be_pg = (const float*)d_in[17];
    const float* Wl_gp = (const float*)d_in[18];
    const float* bl_gp = (const float*)d_in[19];
    const float* Wr_gp = (const float*)d_in[20];
    const float* We_gp = (const float*)d_in[21];
    const float* be_gp = (const float*)d_in[22];
    const float* Wl_ps = (const float*)d_in[23];
    const float* bl_ps = (const float*)d_in[24];
    const float* Wr_ps = (const float*)d_in[25];
    const float* Wl_sp = (const float*)d_in[26];
    const float* bl_sp = (const float*)d_in[27];
    const float* Wr_sp = (const float*)d_in[28];
    const float* W_out = (const float*)d_in[29];
    const float* b_out = (const float*)d_in[30];
    const float* a_pre = (const float*)d_in[31];

    int*   wsi = (int*)d_ws;
    float* wsf = (float*)d_ws;

    // init: counts (cursor region) to 0, maxe to -1
    hipMemsetAsync(wsi + CUR_PG, 0, (size_t)320000 * sizeof(int), stream);
    hipMemsetAsync(wsi + MAXE_PG, 0xFF, (size_t)250000 * sizeof(int), stream);

    int eblocks = (ETOT + 255) / 256;
    hist_all<<<eblocks, 256, 0, stream>>>(dst_pg, dst_gp, dst_sp, dst_ps, wsi);
    scan1_all<<<NB_PG + NB_GP + NB_SP + NB_PS, 256, 0, stream>>>(wsi);
    scan2_all<<<4, 64, 0, stream>>>(wsi);
    scan3_all<<<(NGW + NPFAS + NPFAS + NSW + 4 + 255) / 256, 256, 0, stream>>>(wsi);
    scatter_all<<<eblocks, 256, 0, stream>>>(src_pg, dst_pg, src_gp, dst_gp,
                                             src_sp, dst_sp, src_ps, dst_ps, wsi);
    {
        int ngroups = NGW + NPFAS + NPFAS + NSW;   // 320,000 node-groups
        gather_all<<<(ngroups * 32 + 255) / 256, 256, 0, stream>>>(x_pfas, x_gw, x_sw, wsi);
    }

    // output layout: h_pfas [50000*32] | y [200000] | h_sw [20000*32]
    float* out    = (float*)d_out;
    float* h_pfas = out;
    float* y_out  = out + 1600000;
    float* h_sw   = out + 1800000;

    finalize_pfas<<<(NPFAS + 255) / 256, 256, 0, stream>>>(
        wsf + S_GP, wsi + PTR_GP, wsi + MAXE_GP, wsf + S_SP, wsi + PTR_SP,
        x_pfas, ea_gp,
        Wl_gp, bl_gp, Wr_gp, We_gp, be_gp,
        Wl_sp, bl_sp, Wr_sp, h_pfas);

    finalize_gw<<<(NGW + 255) / 256, 256, 0, stream>>>(
        wsf + S_PG, wsi + PTR_PG, wsi + MAXE_PG, x_gw, ea_pg,
        Wl_pg, bl_pg, Wr_pg, We_pg, be_pg,
        W_out, b_out, a_pre, y_out);

    finalize_sw<<<(NSW + 255) / 256, 256, 0, stream>>>(
        wsf + S_PS, wsi + PTR_PS, x_sw, Wl_ps, bl_ps, Wr_ps, h_sw);
}